// Round 1
// baseline (186.070 us; speedup 1.0000x reference)
//
#include <hip/hip_runtime.h>
#include <cstdint>

#define N 2048
#define NH 8
#define DI 32
#define DOUT 32
#define BATCH 4
#define LOG2E 1.44269504088896340736f

typedef float f32x4 __attribute__((ext_vector_type(4)));
typedef __bf16 bf16x8 __attribute__((ext_vector_type(8)));

__device__ __forceinline__ unsigned short f2bf(float f) {
    unsigned u = __float_as_uint(f);
    u = u + 0x7fffu + ((u >> 16) & 1u);
    return (unsigned short)(u >> 16);
}

// ---------------- K1: pack adj int32 -> bitmask (2 MB) ----------------
__global__ __launch_bounds__(256) void k_pack(const int* __restrict__ adj,
                                              unsigned long long* __restrict__ adjp64) {
    int idx = blockIdx.x * 256 + threadIdx.x;
    unsigned long long m = __ballot(adj[idx] != 0);
    if ((threadIdx.x & 63) == 0) adjp64[idx >> 6] = m;
}

// ---------------- K2: xi, xj, and xh B-fragments (bf16) ----------------
__global__ __launch_bounds__(256) void k_prep(const float* __restrict__ x,
                                              const float* __restrict__ att_w,
                                              float* __restrict__ xi, float* __restrict__ xj,
                                              unsigned short* __restrict__ xhB) {
    int g = blockIdx.x >> 3, chunk = blockIdx.x & 7;
    int b = g >> 3, h = g & 7;
    __shared__ float aw[2 * DI];
    if (threadIdx.x < 2 * DI) aw[threadIdx.x] = att_w[threadIdx.x];
    __syncthreads();

    int i = chunk * 256 + threadIdx.x;
    const float* xr = x + ((size_t)b * N + i) * (NH * DI) + h * DI;
    float si = 0.f, sj = 0.f;
#pragma unroll
    for (int d = 0; d < DI; ++d) {
        float v = xr[d];
        si += v * aw[d];
        sj += v * aw[DI + d];
    }
    xi[g * N + i] = si;
    xj[g * N + i] = sj;

    // B-fragment layout for mfma_f32_16x16x32_bf16:
    // lane holds B[k=(lane>>4)*8+r][col=lane&15]; tiles indexed [g][jt(64)][dh(2)][lane(64)][r(8)]
    for (int t = 0; t < 4; ++t) {
        int item = t * 256 + threadIdx.x;      // 0..1023
        int lane = item & 63;
        int dh = (item >> 6) & 1;
        int jt = chunk * 8 + (item >> 7);      // 0..63
        int d = dh * 16 + (lane & 15);
        int j0 = jt * 32 + (lane >> 4) * 8;
        union { unsigned short u[8]; uint4 v; } f;
#pragma unroll
        for (int r = 0; r < 8; ++r) {
            float v = x[((size_t)b * N + j0 + r) * (NH * DI) + h * DI + d];
            f.u[r] = f2bf(v);
        }
        *(uint4*)(xhB + ((((size_t)g * 64 + jt) * 2 + dh) * 64 + lane) * 8) = f.v;
    }
}

// ---------------- K2b: per-g max of xj ----------------
__global__ __launch_bounds__(256) void k_xjmax(const float* __restrict__ xj,
                                               float* __restrict__ xjmax) {
    int g = blockIdx.x;
    float m = -3.4e38f;
    for (int i = threadIdx.x; i < N; i += 256) m = fmaxf(m, xj[g * N + i]);
#pragma unroll
    for (int off = 32; off >= 1; off >>= 1) m = fmaxf(m, __shfl_xor(m, off, 64));
    __shared__ float red[4];
    if ((threadIdx.x & 63) == 0) red[threadIdx.x >> 6] = m;
    __syncthreads();
    if (threadIdx.x == 0)
        xjmax[g] = fmaxf(fmaxf(red[0], red[1]), fmaxf(red[2], red[3]));
}

// ---------------- K3: main fused kernel ----------------
// grid = 32 g * 32 i-tiles; block = 256 (4 waves); wave w owns rows it*64+16w..+15
__global__ __launch_bounds__(256, 4) void k_main(
    const unsigned* __restrict__ adjp, const float* __restrict__ xi_g,
    const float* __restrict__ xj_g, const float* __restrict__ xjmax_g,
    const unsigned short* __restrict__ xhB, const float* __restrict__ fc_w,
    const float* __restrict__ fc_b, float* __restrict__ out0, float* __restrict__ att) {
    int g = blockIdx.x >> 5;
    int it = blockIdx.x & 31;
    int b = g >> 3, h = g & 7, ab = g & 3;
    int tid = threadIdx.x;
    int w = tid >> 6, l = tid & 63;
    int qg = l >> 4, lr = l & 15;

    __shared__ float xj_s[N];            // 8 KB
    __shared__ unsigned adj_s[64][65];   // 16.6 KB (padded: conflict-free)
    __shared__ float s_s[64];
    __shared__ float fcw_s[32][33];
    __shared__ float fcb_s[32];
    __shared__ float agg_s[64][33];

    // stage xj row (2048 f32)
    {
        const float4* src = (const float4*)(xj_g + (size_t)g * N);
        float4* dst = (float4*)xj_s;
        dst[tid] = src[tid];
        dst[256 + tid] = src[256 + tid];
    }
    // stage packed adj rows for this i-tile (64 rows x 64 words)
    {
        int row = tid >> 2, seg = tid & 3;
        const uint4* src = (const uint4*)(adjp + (((size_t)ab * N) + it * 64 + row) * 64 + seg * 16);
#pragma unroll
        for (int q = 0; q < 4; ++q) {
            uint4 v = src[q];
            unsigned* dst = &adj_s[row][seg * 16 + q * 4];
            dst[0] = v.x; dst[1] = v.y; dst[2] = v.z; dst[3] = v.w;
        }
    }
    if (tid < 32) fcb_s[tid] = fc_b[tid];
    {
        float4 v = ((const float4*)fc_w)[tid];
        int row = tid >> 3, c0 = (tid & 7) * 4;
        fcw_s[row][c0 + 0] = v.x; fcw_s[row][c0 + 1] = v.y;
        fcw_s[row][c0 + 2] = v.z; fcw_s[row][c0 + 3] = v.w;
    }
    __syncthreads();

    int iloc = w * 16 + lr;
    int i = it * 64 + iloc;
    float xiv = xi_g[(size_t)g * N + i];
    float vM = xiv + xjmax_g[g];
    float M = fmaxf(vM, 0.01f * vM);        // unmasked row max (lrelu monotone)
    float nMl = -M * LOG2E;

    f32x4 acc0 = {0.f, 0.f, 0.f, 0.f}, acc1 = {0.f, 0.f, 0.f, 0.f};
    float ssum = 0.f;
    const unsigned short* xb = xhB + (size_t)g * 64 * 2 * 64 * 8;

    // ---- pass 1: denominator + agg MFMA ----
    for (int jt = 0; jt < 64; ++jt) {
        unsigned byte = (adj_s[iloc][jt] >> (qg * 8)) & 0xffu;
        int j0 = jt * 32 + qg * 8;
        f32x4 xa = *(const f32x4*)&xj_s[j0];
        f32x4 xb4 = *(const f32x4*)&xj_s[j0 + 4];
        float e[8];
#pragma unroll
        for (int r = 0; r < 8; ++r) {
            float xjv = (r < 4) ? xa[r] : xb4[r - 4];
            float sc = xiv + xjv;
            sc = fmaxf(sc, 0.01f * sc);
            float p = __builtin_amdgcn_exp2f(fmaf(sc, LOG2E, nMl));
            e[r] = ((byte >> r) & 1u) ? p : 0.f;
            ssum += e[r];
        }
        union { unsigned short u[8]; bf16x8 v; } af;
#pragma unroll
        for (int r = 0; r < 8; ++r) af.u[r] = f2bf(e[r]);
        const bf16x8* bp = (const bf16x8*)(xb + (((size_t)jt * 2) * 64 + l) * 8);
        bf16x8 b0 = bp[0];
        bf16x8 b1 = bp[64];
        acc0 = __builtin_amdgcn_mfma_f32_16x16x32_bf16(af.v, b0, acc0, 0, 0, 0);
        acc1 = __builtin_amdgcn_mfma_f32_16x16x32_bf16(af.v, b1, acc1, 0, 0, 0);
    }

    ssum += __shfl_xor(ssum, 16, 64);
    ssum += __shfl_xor(ssum, 32, 64);
    if (qg == 0) s_s[iloc] = ssum;
    float invA = 1.0f / ssum;
    __syncthreads();

    // ---- pass 2: recompute e, scale, stream att out ----
    float* arow = att + ((size_t)g * N + i) * N;
    for (int jt = 0; jt < 64; ++jt) {
        unsigned byte = (adj_s[iloc][jt] >> (qg * 8)) & 0xffu;
        int j0 = jt * 32 + qg * 8;
        f32x4 xa = *(const f32x4*)&xj_s[j0];
        f32x4 xb4 = *(const f32x4*)&xj_s[j0 + 4];
        f32x4 o0, o1;
#pragma unroll
        for (int r = 0; r < 8; ++r) {
            float xjv = (r < 4) ? xa[r] : xb4[r - 4];
            float sc = xiv + xjv;
            sc = fmaxf(sc, 0.01f * sc);
            float p = __builtin_amdgcn_exp2f(fmaf(sc, LOG2E, nMl)) * invA;
            float av = ((byte >> r) & 1u) ? p : 0.f;
            if (r < 4) o0[r] = av; else o1[r - 4] = av;
        }
        *(f32x4*)&arow[j0] = o0;
        *(f32x4*)&arow[j0 + 4] = o1;
    }

    // ---- epilogue: scale agg, out = relu(agg @ fc_w^T + fc_b) ----
    {
        int r0 = w * 16 + qg * 4;
#pragma unroll
        for (int r = 0; r < 4; ++r) {
            float inv = 1.0f / s_s[r0 + r];
            agg_s[r0 + r][lr] = acc0[r] * inv;
            agg_s[r0 + r][16 + lr] = acc1[r] * inv;
        }
    }
    __syncthreads();
    {
        int orow = w * 16 + lr;
        int do0 = qg * 8;
        float o[8];
#pragma unroll
        for (int r = 0; r < 8; ++r) o[r] = fcb_s[do0 + r];
#pragma unroll
        for (int d = 0; d < 32; ++d) {
            float a = agg_s[orow][d];
#pragma unroll
            for (int r = 0; r < 8; ++r) o[r] = fmaf(a, fcw_s[do0 + r][d], o[r]);
        }
        float4 v0 = make_float4(fmaxf(o[0], 0.f), fmaxf(o[1], 0.f), fmaxf(o[2], 0.f), fmaxf(o[3], 0.f));
        float4 v1 = make_float4(fmaxf(o[4], 0.f), fmaxf(o[5], 0.f), fmaxf(o[6], 0.f), fmaxf(o[7], 0.f));
        float* op = out0 + ((size_t)b * N + it * 64 + orow) * (NH * DOUT) + h * DOUT + do0;
        *(float4*)op = v0;
        *(float4*)(op + 4) = v1;
    }
}

extern "C" void kernel_launch(void* const* d_in, const int* in_sizes, int n_in,
                              void* d_out, int out_size, void* d_ws, size_t ws_size,
                              hipStream_t stream) {
    const float* x = (const float*)d_in[0];
    const int* adj = (const int*)d_in[1];
    const float* att_w = (const float*)d_in[2];
    const float* fc_w = (const float*)d_in[3];
    const float* fc_b = (const float*)d_in[4];

    unsigned char* ws = (unsigned char*)d_ws;
    unsigned long long* adjp64 = (unsigned long long*)ws;                 // 2 MB
    unsigned* adjp = (unsigned*)ws;
    float* xi = (float*)(ws + 2097152);                                   // 256 KB
    float* xj = (float*)(ws + 2359296);                                   // 256 KB
    float* xjmax = (float*)(ws + 2621440);                                // 128 B
    unsigned short* xhB = (unsigned short*)(ws + 2621568);                // 4 MB

    float* out0 = (float*)d_out;
    float* att = out0 + (size_t)BATCH * N * NH * DOUT;                    // +2097152

    k_pack<<<(BATCH * N * N) / 256, 256, 0, stream>>>(adj, adjp64);
    k_prep<<<32 * 8, 256, 0, stream>>>(x, att_w, xi, xj, xhB);
    k_xjmax<<<32, 256, 0, stream>>>(xj, xjmax);
    k_main<<<32 * 32, 256, 0, stream>>>(adjp, xi, xj, xjmax, xhB, fc_w, fc_b, out0, att);
}